// Round 4
// baseline (154.130 us; speedup 1.0000x reference)
//
#include <hip/hip_runtime.h>

#define WIRES   12
#define NSTATE  4096          // 2^12
#define QDEPTH  8
#define BLOCK   256           // 4 waves per block = one batch element
#define PER_T   16            // 4 reg bits; +2 DPP lane bits = 6 wires/phase

using f2 = __attribute__((ext_vector_type(2))) float;

// GF(2) XOR-swizzled LDS layout (UNPADDED 4096 f2): amp a -> slot
// sig(a) = a ^ ((a>>4)&15) ^ ((a>>8)&15). Linear in a, so every affine
// access pattern stays base ^ compile-time-imm. Verified: W1/R1/W2 hit
// each bank-pair exactly 2x per 32-lane group (2-way = free, m136).
__device__ __forceinline__ int sig(int a) { return a ^ ((a >> 4) & 15) ^ ((a >> 8) & 15); }
// sig of the R1/W2 k'-dependent part (k' occupies amp bits 6..9):
constexpr int ck1(int k) { return (k << 6) ^ ((k & 3) << 2) ^ (k >> 2); }

// Column j of the GF(2)-linear CNOT-ring permutation of layer l:
// F = g_0∘g_1∘...∘g_11 (g_11 applied first / innermost).
constexpr int colF(int l, int j) {
    int rr = (l % (WIRES - 1)) + 1;
    int v = 1 << j;
    for (int k = WIRES - 1; k >= 0; --k) {
        int bc = 11 - k;                   // control bit
        int bt = 11 - ((k + rr) % WIRES);  // target bit
        v ^= ((v >> bc) & 1) << bt;
    }
    return v;
}
struct ColsT { int v[QDEPTH][WIRES]; };
constexpr ColsT mkCols() {
    ColsT c{};
    for (int l = 0; l < QDEPTH; ++l)
        for (int j = 0; j < WIRES; ++j) c.v[l][j] = colF(l, j);
    return c;
}
static __device__ const ColsT COLS = mkCols();   // rodata, uniform s_load

// ---- setup kernel: 96 rotation matrices -> d_ws (8 f2 per gate) ----
// Entries pre-expanded for packed math: urr = {re,re}, uw = {-im,+im}.
__global__ void mats_kernel(const float* __restrict__ wts, f2* __restrict__ mg)
{
    int t = blockIdx.x * blockDim.x + threadIdx.x;
    if (t >= QDEPTH * WIRES) return;
    float phi   = tanhf(wts[t * 3 + 0]);
    float theta = tanhf(wts[t * 3 + 1]);
    float omega = tanhf(wts[t * 3 + 2]);
    float c  = cosf(theta * 0.5f);
    float s  = sinf(theta * 0.5f);
    float a  = 0.5f * (phi + omega);
    float bm = 0.5f * (phi - omega);
    float ca = cosf(a),  sa = sinf(a);
    float cb = cosf(bm), sb = sinf(bm);
    // U00 = (c*ca, -c*sa)  U01 = (-s*cb, -s*sb)
    // U10 = (s*cb, -s*sb)  U11 = (c*ca,  c*sa)
    f2* m = mg + t * 8;
    m[0] = f2{ c * ca,  c * ca};   // u00 re,re
    m[1] = f2{ c * sa, -c * sa};   // {-im,+im}, im=-c*sa
    m[2] = f2{-s * cb, -s * cb};   // u01 re,re
    m[3] = f2{ s * sb, -s * sb};   // {-im,+im}, im=-s*sb
    m[4] = f2{ s * cb,  s * cb};   // u10 re,re
    m[5] = f2{ s * sb, -s * sb};   // {-im,+im}, im=-s*sb
    m[6] = f2{ c * ca,  c * ca};   // u11 re,re
    m[7] = f2{-c * sa,  c * sa};   // {-im,+im}, im=+c*sa
}

// 2x2 complex gate on local register bit P. ONE asm block per TWO pairs:
// four accumulator chains issued round-robin so dependent pk-ops are 4
// instructions apart. Perp {-y,x} folded via op_sel.
template<int P>
__device__ __forceinline__ void gate(f2 r[PER_T], const f2* __restrict__ m)
{
    const f2 u00r = m[0], u00w = m[1], u01r = m[2], u01w = m[3];
    const f2 u10r = m[4], u10w = m[5], u11r = m[6], u11w = m[7];
    #pragma unroll
    for (int pr = 0; pr < PER_T / 2; pr += 2) {
        const int k0 = ((pr >> P) << (P + 1)) | (pr & ((1 << P) - 1));
        const int k1 = k0 | (1 << P);
        const int q  = pr + 1;
        const int j0 = ((q >> P) << (P + 1)) | (q & ((1 << P) - 1));
        const int j1 = j0 | (1 << P);
        f2 a0, b0, a1, b1;
        asm("v_pk_mul_f32 %0, %4, %8\n\t"
            "v_pk_mul_f32 %1, %4, %12\n\t"
            "v_pk_mul_f32 %2, %6, %8\n\t"
            "v_pk_mul_f32 %3, %6, %12\n\t"
            "v_pk_fma_f32 %0, %4, %9, %0 op_sel:[1,0,0] op_sel_hi:[0,1,1]\n\t"
            "v_pk_fma_f32 %1, %4, %13, %1 op_sel:[1,0,0] op_sel_hi:[0,1,1]\n\t"
            "v_pk_fma_f32 %2, %6, %9, %2 op_sel:[1,0,0] op_sel_hi:[0,1,1]\n\t"
            "v_pk_fma_f32 %3, %6, %13, %3 op_sel:[1,0,0] op_sel_hi:[0,1,1]\n\t"
            "v_pk_fma_f32 %0, %5, %10, %0\n\t"
            "v_pk_fma_f32 %1, %5, %14, %1\n\t"
            "v_pk_fma_f32 %2, %7, %10, %2\n\t"
            "v_pk_fma_f32 %3, %7, %14, %3\n\t"
            "v_pk_fma_f32 %0, %5, %11, %0 op_sel:[1,0,0] op_sel_hi:[0,1,1]\n\t"
            "v_pk_fma_f32 %1, %5, %15, %1 op_sel:[1,0,0] op_sel_hi:[0,1,1]\n\t"
            "v_pk_fma_f32 %2, %7, %11, %2 op_sel:[1,0,0] op_sel_hi:[0,1,1]\n\t"
            "v_pk_fma_f32 %3, %7, %15, %3 op_sel:[1,0,0] op_sel_hi:[0,1,1]"
            : "=&v"(a0), "=&v"(b0), "=&v"(a1), "=&v"(b1)
            : "v"(r[k0]), "v"(r[k1]), "v"(r[j0]), "v"(r[j1]),
              "v"(u00r), "v"(u00w), "v"(u01r), "v"(u01w),
              "v"(u10r), "v"(u10w), "v"(u11r), "v"(u11w));
        r[k0] = a0; r[k1] = b0; r[j0] = a1; r[j1] = b1;
    }
}

// Cross-lane partner fetch on the VALU pipe (DPP, no LDS).
// CTRL 0xB1 = quad_perm:[1,0,3,2] = lane^1; 0x4E = [2,3,0,1] = lane^2.
template<int CTRL>
__device__ __forceinline__ f2 dpp_xor(f2 v) {
    f2 o;
    o.x = __int_as_float(__builtin_amdgcn_update_dpp(
            0, __float_as_int(v.x), CTRL, 0xF, 0xF, true));
    o.y = __int_as_float(__builtin_amdgcn_update_dpp(
            0, __float_as_int(v.y), CTRL, 0xF, 0xF, true));
    return o;
}

// 2x2 complex gate on a LANE bit (via DPP partner fetch). hb = this
// lane's bit value. out = us*self + uo*partner with
//   hb=0: us=u00, uo=u01;   hb=1: us=u11, uo=u10.
template<int CTRL>
__device__ __forceinline__ void dppgate(f2 r[PER_T], const f2* __restrict__ m, bool hb)
{
    const f2 usr = hb ? m[6] : m[0];
    const f2 usw = hb ? m[7] : m[1];
    const f2 uor = hb ? m[4] : m[2];
    const f2 uow = hb ? m[5] : m[3];
    #pragma unroll
    for (int k0 = 0; k0 < PER_T; k0 += 4) {
        f2 p0 = dpp_xor<CTRL>(r[k0 + 0]);
        f2 p1 = dpp_xor<CTRL>(r[k0 + 1]);
        f2 p2 = dpp_xor<CTRL>(r[k0 + 2]);
        f2 p3 = dpp_xor<CTRL>(r[k0 + 3]);
        f2 a0, a1, a2, a3;
        asm("v_pk_mul_f32 %0, %4, %12\n\t"
            "v_pk_mul_f32 %1, %5, %12\n\t"
            "v_pk_mul_f32 %2, %6, %12\n\t"
            "v_pk_mul_f32 %3, %7, %12\n\t"
            "v_pk_fma_f32 %0, %4, %13, %0 op_sel:[1,0,0] op_sel_hi:[0,1,1]\n\t"
            "v_pk_fma_f32 %1, %5, %13, %1 op_sel:[1,0,0] op_sel_hi:[0,1,1]\n\t"
            "v_pk_fma_f32 %2, %6, %13, %2 op_sel:[1,0,0] op_sel_hi:[0,1,1]\n\t"
            "v_pk_fma_f32 %3, %7, %13, %3 op_sel:[1,0,0] op_sel_hi:[0,1,1]\n\t"
            "v_pk_fma_f32 %0, %8, %14, %0\n\t"
            "v_pk_fma_f32 %1, %9, %14, %1\n\t"
            "v_pk_fma_f32 %2, %10, %14, %2\n\t"
            "v_pk_fma_f32 %3, %11, %14, %3\n\t"
            "v_pk_fma_f32 %0, %8, %15, %0 op_sel:[1,0,0] op_sel_hi:[0,1,1]\n\t"
            "v_pk_fma_f32 %1, %9, %15, %1 op_sel:[1,0,0] op_sel_hi:[0,1,1]\n\t"
            "v_pk_fma_f32 %2, %10, %15, %2 op_sel:[1,0,0] op_sel_hi:[0,1,1]\n\t"
            "v_pk_fma_f32 %3, %11, %15, %3 op_sel:[1,0,0] op_sel_hi:[0,1,1]"
            : "=&v"(a0), "=&v"(a1), "=&v"(a2), "=&v"(a3)
            : "v"(r[k0]), "v"(r[k0 + 1]), "v"(r[k0 + 2]), "v"(r[k0 + 3]),
              "v"(p0), "v"(p1), "v"(p2), "v"(p3),
              "v"(usr), "v"(usw), "v"(uor), "v"(uow));
        r[k0] = a0; r[k0 + 1] = a1; r[k0 + 2] = a2; r[k0 + 3] = a3;
    }
}

// 4 waves = one batch element. g = threadIdx.x (8 bits).
// Canonical: r[k] = amp[(g<<4)|k]  (amp bit b <-> wire 11-b).
// Per layer, TWO phases of 6 wires each (4 reg bits + 2 DPP lane bits):
//   P1: amp bits 0..5  = wires 11..6  (k bits + lane^1, lane^2)
//   T1: k' <- amp bits 9..6; lane bits 0,1 <- amp bits 10,11
//   P2: amp bits 6..11 = wires 5..0
//   T2: scatter + gather canonical ∘ F (CNOT ring folded in)
// 3 barriers/layer. No barrier between R1-consume and W2 (same per-lane
// slot set, bijective). LDS ops/layer: 48+16F vs round-1's 96 (-33%).
__global__ __launch_bounds__(BLOCK, 4) void qsim_kernel(
    const float* __restrict__ x,
    const f2*    __restrict__ mats_g,
    const int*   __restrict__ reps_ptr,
    float*       __restrict__ out,
    int write_mode)
{
    __shared__ f2 st[4096];                          // 32768 B, unpadded

    const int g  = threadIdx.x;
    const int b  = blockIdx.x;
    const bool hb0 = (g & 1) != 0;   // lane bit 0 parity (amp bit 4 / 10)
    const bool hb1 = (g & 2) != 0;   // lane bit 1 parity (amp bit 5 / 11)

    // W1: amp a=(g<<4)|k -> slot (g<<4) | (k ^ hg)
    const int hg  = (g ^ (g >> 4)) & 15;
    const int w1b = g << 4;
    // R1/W2: lane holds amps A(g) | (k'<<6), slot = sig(A) ^ ck1(k')
    const int A   = ((g >> 2) & 15) | (((g >> 6) & 3) << 4) | ((g & 3) << 10);
    const int r1b = sig(A);

    // ---- load: lane g holds amps (g<<4)|k, k=0..15 (64B contiguous) ----
    const float4* xb4 = (const float4*)(x + (size_t)b * NSTATE) + g * 4;
    f2 r[PER_T];
    #pragma unroll
    for (int c = 0; c < 4; ++c) {
        float4 v = xb4[c];
        r[4*c+0] = f2{v.x, 0.f};
        r[4*c+1] = f2{v.y, 0.f};
        r[4*c+2] = f2{v.z, 0.f};
        r[4*c+3] = f2{v.w, 0.f};
    }

    const int reps = reps_ptr[0];
    for (int rep = 0; rep < reps; ++rep) {
        #pragma unroll 1
        for (int l = 0; l < QDEPTH; ++l) {
            const f2* M = mats_g + l * WIRES * 8;   // wave-uniform -> s_load

            // Phase 1: wires 11..8 on reg bits, wires 7,6 on lane bits
            gate<0>(r, M + 11*8); gate<1>(r, M + 10*8);
            gate<2>(r, M + 9*8);  gate<3>(r, M + 8*8);
            dppgate<0xB1>(r, M + 7*8, hb0);   // amp bit 4
            dppgate<0x4E>(r, M + 6*8, hb1);   // amp bit 5

            // W1: scatter canonical (swizzled)
            #pragma unroll
            for (int k = 0; k < PER_T; ++k) st[w1b + (hg ^ k)] = r[k];
            __syncthreads();
            // R1: gather amp bits 9..6 -> regs, 10,11 -> lane bits
            #pragma unroll
            for (int k = 0; k < PER_T; ++k) r[k] = st[r1b ^ ck1(k)];
            // no barrier: W2 rewrites exactly the slots this lane read

            // Phase 2: wires 5..2 on reg bits, wires 1,0 on lane bits
            gate<0>(r, M + 5*8); gate<1>(r, M + 4*8);
            gate<2>(r, M + 3*8); gate<3>(r, M + 2*8);
            dppgate<0xB1>(r, M + 1*8, hb0);   // amp bit 10
            dppgate<0x4E>(r, M + 0*8, hb1);   // amp bit 11

            #pragma unroll
            for (int k = 0; k < PER_T; ++k) st[r1b ^ ck1(k)] = r[k];
            __syncthreads();

            // F-gather: r[k] = old_amp[F((g<<4)|k)] -> canonical again.
            // sig is GF(2)-linear: slot = sig(FA) ^ sig(ck).
            int FA = 0;
            #pragma unroll
            for (int j = 0; j < 8; ++j)
                FA ^= ((g >> j) & 1) ? COLS.v[l][4 + j] : 0;
            const int fb = sig(FA);
            const int t0 = sig(COLS.v[l][0]), t1 = sig(COLS.v[l][1]);
            const int t2 = sig(COLS.v[l][2]), t3 = sig(COLS.v[l][3]);
            #pragma unroll
            for (int k = 0; k < PER_T; ++k) {
                int ct = ((k & 1) ? t0 : 0) ^ ((k & 2) ? t1 : 0) ^
                         ((k & 4) ? t2 : 0) ^ ((k & 8) ? t3 : 0);
                r[k] = st[fb ^ ct];
            }
            __syncthreads();   // protect next layer's W1 scatter
        }
    }

    // ---- write out (r is canonical: 16 consecutive amps per lane) ----
    if (write_mode == 0) {
        // harness views complex output as float32 real part
        float4* ob4 = (float4*)(out + (size_t)b * NSTATE) + g * 4;
        #pragma unroll
        for (int c = 0; c < 4; ++c)
            ob4[c] = make_float4(r[4*c].x, r[4*c+1].x, r[4*c+2].x, r[4*c+3].x);
    } else {
        float4* ob4 = (float4*)((float2*)out + (size_t)b * NSTATE) + g * 8;
        #pragma unroll
        for (int k = 0; k < PER_T; k += 2)
            ob4[k >> 1] = make_float4(r[k].x, r[k].y, r[k+1].x, r[k+1].y);
    }
}

extern "C" void kernel_launch(void* const* d_in, const int* in_sizes, int n_in,
                              void* d_out, int out_size, void* d_ws, size_t ws_size,
                              hipStream_t stream) {
    const float* x    = (const float*)d_in[0];
    const float* wts  = (const float*)d_in[1];
    const int*   reps = (const int*)d_in[2];
    float*       out  = (float*)d_out;
    f2*          mg   = (f2*)d_ws;            // 96 gates * 8 f2 = 3 KB scratch
    (void)in_sizes; (void)n_in; (void)ws_size;

    const int write_mode = (out_size >= 2 * 1024 * NSTATE) ? 1 : 0;

    mats_kernel<<<1, 128, 0, stream>>>(wts, mg);
    qsim_kernel<<<1024, BLOCK, 0, stream>>>(x, mg, reps, out, write_mode);
}

// Round 5
// 151.752 us; speedup vs baseline: 1.0157x; 1.0157x over previous
//
#include <hip/hip_runtime.h>

#define WIRES   12
#define NSTATE  4096          // 2^12
#define QDEPTH  8
#define BLOCK   256           // 4 waves; block pipelines TWO batch elements
#define PER_T   16            // 4 local index bits per element

using f2 = __attribute__((ext_vector_type(2))) float;

// Pitch-17 padded layout per element buffer: amp a -> f2-slot a + (a>>4).
// Affine in local index k for all three transpose patterns -> ds
// addresses are base + compile-time immediate. (Proven in R1.)
__device__ __forceinline__ int slotf(int a) { return a + (a >> 4); }

// Column j of the GF(2)-linear CNOT-ring permutation of layer l:
// F = g_0∘g_1∘...∘g_11 (g_11 applied first / innermost).
constexpr int colF(int l, int j) {
    int rr = (l % (WIRES - 1)) + 1;
    int v = 1 << j;
    for (int k = WIRES - 1; k >= 0; --k) {
        int bc = 11 - k;                   // control bit
        int bt = 11 - ((k + rr) % WIRES);  // target bit
        v ^= ((v >> bc) & 1) << bt;
    }
    return v;
}
struct ColsT { int v[QDEPTH][WIRES]; };
constexpr ColsT mkCols() {
    ColsT c{};
    for (int l = 0; l < QDEPTH; ++l)
        for (int j = 0; j < WIRES; ++j) c.v[l][j] = colF(l, j);
    return c;
}
static __device__ const ColsT COLS = mkCols();   // rodata, uniform s_load

// ---- setup kernel: 96 rotation matrices -> d_ws (8 f2 per gate) ----
// Entries pre-expanded for packed math: urr = {re,re}, uw = {-im,+im}.
__global__ void mats_kernel(const float* __restrict__ wts, f2* __restrict__ mg)
{
    int t = blockIdx.x * blockDim.x + threadIdx.x;
    if (t >= QDEPTH * WIRES) return;
    float phi   = tanhf(wts[t * 3 + 0]);
    float theta = tanhf(wts[t * 3 + 1]);
    float omega = tanhf(wts[t * 3 + 2]);
    float c  = cosf(theta * 0.5f);
    float s  = sinf(theta * 0.5f);
    float a  = 0.5f * (phi + omega);
    float bm = 0.5f * (phi - omega);
    float ca = cosf(a),  sa = sinf(a);
    float cb = cosf(bm), sb = sinf(bm);
    // U00 = (c*ca, -c*sa)  U01 = (-s*cb, -s*sb)
    // U10 = (s*cb, -s*sb)  U11 = (c*ca,  c*sa)
    f2* m = mg + t * 8;
    m[0] = f2{ c * ca,  c * ca};   // u00 re,re
    m[1] = f2{ c * sa, -c * sa};   // {-im,+im}, im=-c*sa
    m[2] = f2{-s * cb, -s * cb};   // u01 re,re
    m[3] = f2{ s * sb, -s * sb};   // {-im,+im}, im=-s*sb
    m[4] = f2{ s * cb,  s * cb};   // u10 re,re
    m[5] = f2{ s * sb, -s * sb};   // {-im,+im}, im=-s*sb
    m[6] = f2{ c * ca,  c * ca};   // u11 re,re
    m[7] = f2{-c * sa,  c * sa};   // {-im,+im}, im=+c*sa
}

// 2x2 complex gate on local register bit P. ONE asm block per TWO pairs:
// four accumulator chains (a0,b0,a1,b1) issued round-robin so dependent
// pk-ops are 4 instructions apart. Perp {-y,x} folded via op_sel.
template<int P>
__device__ __forceinline__ void gate(f2 r[PER_T], const f2* __restrict__ m)
{
    const f2 u00r = m[0], u00w = m[1], u01r = m[2], u01w = m[3];
    const f2 u10r = m[4], u10w = m[5], u11r = m[6], u11w = m[7];
    #pragma unroll
    for (int pr = 0; pr < PER_T / 2; pr += 2) {
        const int k0 = ((pr >> P) << (P + 1)) | (pr & ((1 << P) - 1));
        const int k1 = k0 | (1 << P);
        const int q  = pr + 1;
        const int j0 = ((q >> P) << (P + 1)) | (q & ((1 << P) - 1));
        const int j1 = j0 | (1 << P);
        f2 a0, b0, a1, b1;
        asm("v_pk_mul_f32 %0, %4, %8\n\t"
            "v_pk_mul_f32 %1, %4, %12\n\t"
            "v_pk_mul_f32 %2, %6, %8\n\t"
            "v_pk_mul_f32 %3, %6, %12\n\t"
            "v_pk_fma_f32 %0, %4, %9, %0 op_sel:[1,0,0] op_sel_hi:[0,1,1]\n\t"
            "v_pk_fma_f32 %1, %4, %13, %1 op_sel:[1,0,0] op_sel_hi:[0,1,1]\n\t"
            "v_pk_fma_f32 %2, %6, %9, %2 op_sel:[1,0,0] op_sel_hi:[0,1,1]\n\t"
            "v_pk_fma_f32 %3, %6, %13, %3 op_sel:[1,0,0] op_sel_hi:[0,1,1]\n\t"
            "v_pk_fma_f32 %0, %5, %10, %0\n\t"
            "v_pk_fma_f32 %1, %5, %14, %1\n\t"
            "v_pk_fma_f32 %2, %7, %10, %2\n\t"
            "v_pk_fma_f32 %3, %7, %14, %3\n\t"
            "v_pk_fma_f32 %0, %5, %11, %0 op_sel:[1,0,0] op_sel_hi:[0,1,1]\n\t"
            "v_pk_fma_f32 %1, %5, %15, %1 op_sel:[1,0,0] op_sel_hi:[0,1,1]\n\t"
            "v_pk_fma_f32 %2, %7, %11, %2 op_sel:[1,0,0] op_sel_hi:[0,1,1]\n\t"
            "v_pk_fma_f32 %3, %7, %15, %3 op_sel:[1,0,0] op_sel_hi:[0,1,1]"
            : "=&v"(a0), "=&v"(b0), "=&v"(a1), "=&v"(b1)
            : "v"(r[k0]), "v"(r[k1]), "v"(r[j0]), "v"(r[j1]),
              "v"(u00r), "v"(u00w), "v"(u01r), "v"(u01w),
              "v"(u10r), "v"(u10w), "v"(u11r), "v"(u11w));
        r[k0] = a0; r[k1] = b0; r[j0] = a1; r[j1] = b1;
    }
}

// One 4-wire gate phase. PH=0 -> wires 8..11 (amp bits 3..0 local),
// PH=1 -> wires 4..7, PH=2 -> wires 0..3. (R1 mapping, proven.)
template<int PH>
__device__ __forceinline__ void gphase(f2 r[PER_T], const f2* __restrict__ M)
{
    const int base = (2 - PH) * 4;
    gate<3>(r, M + (base + 0) * 8); gate<2>(r, M + (base + 1) * 8);
    gate<1>(r, M + (base + 2) * 8); gate<0>(r, M + (base + 3) * 8);
}

// F-gather: r[k] = state[F((g<<4)|k)] from pad-17 buffer (R1, proven).
__device__ __forceinline__ void fread(f2 r[PER_T], const f2* __restrict__ st,
                                      int l, int g)
{
    int Fg = 0;
    #pragma unroll
    for (int j = 0; j < 8; ++j)
        Fg ^= ((g >> j) & 1) ? COLS.v[l][4 + j] : 0;
    const int c0 = COLS.v[l][0], c1 = COLS.v[l][1];
    const int c2 = COLS.v[l][2], c3 = COLS.v[l][3];
    #pragma unroll
    for (int k = 0; k < PER_T; ++k) {
        int ck = ((k & 1) ? c0 : 0) ^ ((k & 2) ? c1 : 0) ^
                 ((k & 4) ? c2 : 0) ^ ((k & 8) ? c3 : 0);
        r[k] = st[slotf(Fg ^ ck)];
    }
}

// 4 waves = TWO batch elements, software-pipelined one period apart.
// Canonical: r[k] = amp[(g<<4)|k]. Element flow per layer (R1 rounds):
//   G_P1 -> W1 -> R1 -> G_P2 -> W2 -> R2 -> G_P3 -> W3 -> FR(F-fold)
// Periods (one barrier each; X gates while Y's ds-round is in flight):
//   p0: G1(A) | FR(B,prev) | W1(A)     p1: G1(B) | R1(A) | W1(B)
//   p2: G2(A) | R1(B) | W2(A)          p3: G2(B) | R2(A) | W2(B)
//   p4: G3(A) | R2(B) | W3(A)          p5: G3(B) | FR(A,l) | W3(B)
// Every read's values are consumed one full period later -> LDS latency
// and bandwidth hide under the other element's pure-VALU gate phase.
// All cross-wave W->R hazards are barrier-separated.
__global__ __launch_bounds__(BLOCK, 2) void qsim_kernel(
    const float* __restrict__ x,
    const f2*    __restrict__ mats_g,
    const int*   __restrict__ reps_ptr,
    float*       __restrict__ out,
    int write_mode)
{
    __shared__ f2 st[2 * 4352];                      // 69632 B -> 2 blocks/CU
    f2* const sA = st;
    f2* const sB = st + 4352;

    const int g   = threadIdx.x;
    const int eA  = blockIdx.x * 2;
    const int eB  = eA + 1;
    const int ghi = g >> 4, glo = g & 15;
    const int w1b = 17 * g;                // slot((g<<4)|k)          = 17g + k
    const int rb1 = 272 * ghi + glo;       // slot((ghi<<8)|(k<<4)|glo) - 17k
    const int rb2 = 17 * ghi + glo;        // slot((k<<8)|(ghi<<4)|glo) - 272k

    // ---- load: lane g holds amps (g<<4)|k for both elements ----
    const float4* xA4 = (const float4*)(x + (size_t)eA * NSTATE) + g * 4;
    const float4* xB4 = (const float4*)(x + (size_t)eB * NSTATE) + g * 4;
    f2 rA[PER_T], rB[PER_T];
    #pragma unroll
    for (int c = 0; c < 4; ++c) {
        float4 va = xA4[c];
        rA[4*c+0] = f2{va.x, 0.f}; rA[4*c+1] = f2{va.y, 0.f};
        rA[4*c+2] = f2{va.z, 0.f}; rA[4*c+3] = f2{va.w, 0.f};
        float4 vb = xB4[c];
        rB[4*c+0] = f2{vb.x, 0.f}; rB[4*c+1] = f2{vb.y, 0.f};
        rB[4*c+2] = f2{vb.z, 0.f}; rB[4*c+3] = f2{vb.w, 0.f};
    }

    const int reps = reps_ptr[0];
    int pl = -1;                                     // B's pending-F layer
    for (int rep = 0; rep < reps; ++rep) {
        #pragma unroll 1
        for (int l = 0; l < QDEPTH; ++l) {
            const f2* M = mats_g + l * WIRES * 8;   // wave-uniform -> s_load

            // p0: A gates P1; B's layer-(pl) F-gather in flight; W1(A)
            gphase<0>(rA, M);
            if (pl >= 0) fread(rB, sB, pl, g);
            #pragma unroll
            for (int k = 0; k < PER_T; ++k) sA[w1b + k] = rA[k];
            __syncthreads();

            // p1: B gates P1; R1(A) in flight; W1(B)
            gphase<0>(rB, M);
            #pragma unroll
            for (int k = 0; k < PER_T; ++k) rA[k] = sA[rb1 + 17 * k];
            #pragma unroll
            for (int k = 0; k < PER_T; ++k) sB[w1b + k] = rB[k];
            __syncthreads();

            // p2: A gates P2; R1(B) in flight; W2(A)
            gphase<1>(rA, M);
            #pragma unroll
            for (int k = 0; k < PER_T; ++k) rB[k] = sB[rb1 + 17 * k];
            #pragma unroll
            for (int k = 0; k < PER_T; ++k) sA[rb1 + 17 * k] = rA[k];
            __syncthreads();

            // p3: B gates P2; R2(A) in flight; W2(B)
            gphase<1>(rB, M);
            #pragma unroll
            for (int k = 0; k < PER_T; ++k) rA[k] = sA[rb2 + 272 * k];
            #pragma unroll
            for (int k = 0; k < PER_T; ++k) sB[rb1 + 17 * k] = rB[k];
            __syncthreads();

            // p4: A gates P3; R2(B) in flight; W3(A)
            gphase<2>(rA, M);
            #pragma unroll
            for (int k = 0; k < PER_T; ++k) rB[k] = sB[rb2 + 272 * k];
            #pragma unroll
            for (int k = 0; k < PER_T; ++k) sA[rb2 + 272 * k] = rA[k];
            __syncthreads();

            // p5: B gates P3; FR(A, l) in flight; W3(B)
            gphase<2>(rB, M);
            fread(rA, sA, l, g);
            #pragma unroll
            for (int k = 0; k < PER_T; ++k) sB[rb2 + 272 * k] = rB[k];
            __syncthreads();

            pl = l;
        }
    }
    // epilogue: B's final F-gather (A's landed at the last p5)
    if (pl >= 0) fread(rB, sB, pl, g);

    // ---- write out (r is canonical: 16 consecutive amps per lane) ----
    if (write_mode == 0) {
        // harness views complex output as float32 real part
        float4* oA4 = (float4*)(out + (size_t)eA * NSTATE) + g * 4;
        float4* oB4 = (float4*)(out + (size_t)eB * NSTATE) + g * 4;
        #pragma unroll
        for (int c = 0; c < 4; ++c) {
            oA4[c] = make_float4(rA[4*c].x, rA[4*c+1].x, rA[4*c+2].x, rA[4*c+3].x);
            oB4[c] = make_float4(rB[4*c].x, rB[4*c+1].x, rB[4*c+2].x, rB[4*c+3].x);
        }
    } else {
        float4* oA4 = (float4*)((float2*)out + (size_t)eA * NSTATE) + g * 8;
        float4* oB4 = (float4*)((float2*)out + (size_t)eB * NSTATE) + g * 8;
        #pragma unroll
        for (int k = 0; k < PER_T; k += 2) {
            oA4[k >> 1] = make_float4(rA[k].x, rA[k].y, rA[k+1].x, rA[k+1].y);
            oB4[k >> 1] = make_float4(rB[k].x, rB[k].y, rB[k+1].x, rB[k+1].y);
        }
    }
}

extern "C" void kernel_launch(void* const* d_in, const int* in_sizes, int n_in,
                              void* d_out, int out_size, void* d_ws, size_t ws_size,
                              hipStream_t stream) {
    const float* x    = (const float*)d_in[0];
    const float* wts  = (const float*)d_in[1];
    const int*   reps = (const int*)d_in[2];
    float*       out  = (float*)d_out;
    f2*          mg   = (f2*)d_ws;            // 96 gates * 8 f2 = 3 KB scratch
    (void)in_sizes; (void)n_in; (void)ws_size;

    const int write_mode = (out_size >= 2 * 1024 * NSTATE) ? 1 : 0;

    mats_kernel<<<1, 128, 0, stream>>>(wts, mg);
    qsim_kernel<<<512, BLOCK, 0, stream>>>(x, mg, reps, out, write_mode);
}

// Round 6
// 146.089 us; speedup vs baseline: 1.0550x; 1.0388x over previous
//
#include <hip/hip_runtime.h>

#define WIRES   12
#define NSTATE  4096          // 2^12
#define QDEPTH  8
#define BLOCK   256           // 4 waves per block = one batch element
#define PER_T   16            // 4 local index bits; state in 32 VGPRs

using f2 = __attribute__((ext_vector_type(2))) float;

// Pitch-17 padded layout: amp a -> f2-slot a + (a>>4) (rows of 16 f2,
// pitch 17). Affine in local index k for all three transpose patterns ->
// ds addresses are base + compile-time immediate. (Proven in R1.)
__device__ __forceinline__ int slotf(int a) { return a + (a >> 4); }

// Column j of the GF(2)-linear CNOT-ring permutation of layer l:
// F = g_0∘g_1∘...∘g_11 (g_11 applied first / innermost).
constexpr int colF(int l, int j) {
    int rr = (l % (WIRES - 1)) + 1;
    int v = 1 << j;
    for (int k = WIRES - 1; k >= 0; --k) {
        int bc = 11 - k;                   // control bit
        int bt = 11 - ((k + rr) % WIRES);  // target bit
        v ^= ((v >> bc) & 1) << bt;
    }
    return v;
}
struct ColsT { int v[QDEPTH][WIRES]; };
constexpr ColsT mkCols() {
    ColsT c{};
    for (int l = 0; l < QDEPTH; ++l)
        for (int j = 0; j < WIRES; ++j) c.v[l][j] = colF(l, j);
    return c;
}
static __device__ const ColsT COLS = mkCols();   // rodata, uniform s_load

// ---- setup kernel: 96 rotation matrices -> d_ws (8 f2 per gate) ----
// Entries pre-expanded for packed math: urr = {re,re}, uw = {-im,+im}.
__global__ void mats_kernel(const float* __restrict__ wts, f2* __restrict__ mg)
{
    int t = blockIdx.x * blockDim.x + threadIdx.x;
    if (t >= QDEPTH * WIRES) return;
    float phi   = tanhf(wts[t * 3 + 0]);
    float theta = tanhf(wts[t * 3 + 1]);
    float omega = tanhf(wts[t * 3 + 2]);
    float c  = cosf(theta * 0.5f);
    float s  = sinf(theta * 0.5f);
    float a  = 0.5f * (phi + omega);
    float bm = 0.5f * (phi - omega);
    float ca = cosf(a),  sa = sinf(a);
    float cb = cosf(bm), sb = sinf(bm);
    // U00 = (c*ca, -c*sa)  U01 = (-s*cb, -s*sb)
    // U10 = (s*cb, -s*sb)  U11 = (c*ca,  c*sa)
    f2* m = mg + t * 8;
    m[0] = f2{ c * ca,  c * ca};   // u00 re,re
    m[1] = f2{ c * sa, -c * sa};   // {-im,+im}, im=-c*sa
    m[2] = f2{-s * cb, -s * cb};   // u01 re,re
    m[3] = f2{ s * sb, -s * sb};   // {-im,+im}, im=-s*sb
    m[4] = f2{ s * cb,  s * cb};   // u10 re,re
    m[5] = f2{ s * sb, -s * sb};   // {-im,+im}, im=-s*sb
    m[6] = f2{ c * ca,  c * ca};   // u11 re,re
    m[7] = f2{-c * sa,  c * sa};   // {-im,+im}, im=+c*sa
}

// Core: apply the 2x2 complex gate to TWO pairs (x0,x1),(y0,y1) in one
// asm block. Four accumulator chains issued round-robin so dependent
// pk-ops are 4 instructions apart. Perp {-y,x} folded via op_sel.
__device__ __forceinline__ void g2p(f2& x0, f2& x1, f2& y0, f2& y1,
                                    const f2* __restrict__ m)
{
    const f2 u00r = m[0], u00w = m[1], u01r = m[2], u01w = m[3];
    const f2 u10r = m[4], u10w = m[5], u11r = m[6], u11w = m[7];
    f2 a0, b0, a1, b1;
    asm("v_pk_mul_f32 %0, %4, %8\n\t"
        "v_pk_mul_f32 %1, %4, %12\n\t"
        "v_pk_mul_f32 %2, %6, %8\n\t"
        "v_pk_mul_f32 %3, %6, %12\n\t"
        "v_pk_fma_f32 %0, %4, %9, %0 op_sel:[1,0,0] op_sel_hi:[0,1,1]\n\t"
        "v_pk_fma_f32 %1, %4, %13, %1 op_sel:[1,0,0] op_sel_hi:[0,1,1]\n\t"
        "v_pk_fma_f32 %2, %6, %9, %2 op_sel:[1,0,0] op_sel_hi:[0,1,1]\n\t"
        "v_pk_fma_f32 %3, %6, %13, %3 op_sel:[1,0,0] op_sel_hi:[0,1,1]\n\t"
        "v_pk_fma_f32 %0, %5, %10, %0\n\t"
        "v_pk_fma_f32 %1, %5, %14, %1\n\t"
        "v_pk_fma_f32 %2, %7, %10, %2\n\t"
        "v_pk_fma_f32 %3, %7, %14, %3\n\t"
        "v_pk_fma_f32 %0, %5, %11, %0 op_sel:[1,0,0] op_sel_hi:[0,1,1]\n\t"
        "v_pk_fma_f32 %1, %5, %15, %1 op_sel:[1,0,0] op_sel_hi:[0,1,1]\n\t"
        "v_pk_fma_f32 %2, %7, %11, %2 op_sel:[1,0,0] op_sel_hi:[0,1,1]\n\t"
        "v_pk_fma_f32 %3, %7, %15, %3 op_sel:[1,0,0] op_sel_hi:[0,1,1]"
        : "=&v"(a0), "=&v"(b0), "=&v"(a1), "=&v"(b1)
        : "v"(x0), "v"(x1), "v"(y0), "v"(y1),
          "v"(u00r), "v"(u00w), "v"(u01r), "v"(u01w),
          "v"(u10r), "v"(u10w), "v"(u11r), "v"(u11w));
    x0 = a0; x1 = b0; y0 = a1; y1 = b1;
}

#define SBAR() __builtin_amdgcn_sched_barrier(0)

// 4 waves = one batch element. g = threadIdx.x (8 bits).
// Canonical: r[k] = amp[(g<<4)|k]  (amp bit b <-> wire 11-b).
// Per layer, 3 phases of 4 wires (R1 geometry), but LDS ops are
// interleaved INSIDE each phase using gate commutativity:
//   reads -> quad-local gates (bit1,bit0 per quad, as data arrives)
//         -> bit2 gate -> bit3 gate in 4 chunks, each chunk's 4
//            finalized regs written to LDS immediately.
// Only the final chunk's writes + the F-gather burst stay exposed at
// barriers. 4 barriers/layer; same-slot R->W needs no barrier (lane-
// private slot sets, proven in R1).
__global__ __launch_bounds__(BLOCK, 4) void qsim_kernel(
    const float* __restrict__ x,
    const f2*    __restrict__ mats_g,
    const int*   __restrict__ reps_ptr,
    float*       __restrict__ out,
    int write_mode)
{
    __shared__ f2 st[4352];                          // 34816 B -> 4 blocks/CU

    const int g   = threadIdx.x;
    const int b   = blockIdx.x;
    const int ghi = g >> 4, glo = g & 15;
    const int w1b = 17 * g;                // slot((g<<4)|k)          = 17g + k
    const int rb1 = 272 * ghi + glo;       // slot((ghi<<8)|(k<<4)|glo) - 17k
    const int rb2 = 17 * ghi + glo;        // slot((k<<8)|(ghi<<4)|glo) - 272k

    // ---- load: lane g holds amps (g<<4)|k, k=0..15 (64B contiguous) ----
    const float4* xb4 = (const float4*)(x + (size_t)b * NSTATE) + g * 4;
    f2 r[PER_T];
    #pragma unroll
    for (int c = 0; c < 4; ++c) {
        float4 v = xb4[c];
        r[4*c+0] = f2{v.x, 0.f};
        r[4*c+1] = f2{v.y, 0.f};
        r[4*c+2] = f2{v.z, 0.f};
        r[4*c+3] = f2{v.w, 0.f};
    }

    const int reps = reps_ptr[0];
    for (int rep = 0; rep < reps; ++rep) {
        #pragma unroll 1
        for (int l = 0; l < QDEPTH; ++l) {
            const f2* M = mats_g + l * WIRES * 8;   // wave-uniform -> s_load

            // ======== P1: wires 8..11 on local bits 3..0 ========
            {
                const f2 *m3 = M + 8*8, *m2 = M + 9*8;
                const f2 *m1 = M + 10*8, *m0 = M + 11*8;
                // quad-local gates (bit1 then bit0) -- commute with the rest
                #pragma unroll
                for (int j = 0; j < 4; ++j) {
                    g2p(r[4*j], r[4*j+2], r[4*j+1], r[4*j+3], m1);
                    g2p(r[4*j], r[4*j+1], r[4*j+2], r[4*j+3], m0);
                }
                // bit2 (pairs k, k^4)
                g2p(r[0], r[4],  r[1], r[5],  m2);
                g2p(r[2], r[6],  r[3], r[7],  m2);
                g2p(r[8], r[12], r[9], r[13], m2);
                g2p(r[10],r[14], r[11],r[15], m2);
                // bit3 chunked (pairs k, k^8); write each chunk's 4 regs now
                #pragma unroll
                for (int c = 0; c < 8; c += 2) {
                    g2p(r[c], r[c+8], r[c+1], r[c+9], m3);
                    st[w1b + c]     = r[c];
                    st[w1b + c + 1] = r[c+1];
                    st[w1b + c + 8] = r[c+8];
                    st[w1b + c + 9] = r[c+9];
                    SBAR();
                }
            }
            __syncthreads();

            // R1: gather amp bits 7..4 local; consumed quad-by-quad below
            #pragma unroll
            for (int k = 0; k < PER_T; ++k) r[k] = st[rb1 + 17 * k];

            // ======== P2: wires 4..7 on local bits 3..0 ========
            {
                const f2 *m3 = M + 4*8, *m2 = M + 5*8;
                const f2 *m1 = M + 6*8, *m0 = M + 7*8;
                #pragma unroll
                for (int j = 0; j < 4; ++j) {       // waits lgkm per quad
                    g2p(r[4*j], r[4*j+2], r[4*j+1], r[4*j+3], m1);
                    g2p(r[4*j], r[4*j+1], r[4*j+2], r[4*j+3], m0);
                }
                g2p(r[0], r[4],  r[1], r[5],  m2);
                g2p(r[2], r[6],  r[3], r[7],  m2);
                g2p(r[8], r[12], r[9], r[13], m2);
                g2p(r[10],r[14], r[11],r[15], m2);
                #pragma unroll
                for (int c = 0; c < 8; c += 2) {    // W2: same slots as R1
                    g2p(r[c], r[c+8], r[c+1], r[c+9], m3);
                    st[rb1 + 17*c]       = r[c];
                    st[rb1 + 17*(c+1)]   = r[c+1];
                    st[rb1 + 17*(c+8)]   = r[c+8];
                    st[rb1 + 17*(c+9)]   = r[c+9];
                    SBAR();
                }
            }
            __syncthreads();

            // R2: gather amp bits 11..8 local
            #pragma unroll
            for (int k = 0; k < PER_T; ++k) r[k] = st[rb2 + 272 * k];

            // ======== P3: wires 0..3 on local bits 3..0 ========
            {
                const f2 *m3 = M + 0*8, *m2 = M + 1*8;
                const f2 *m1 = M + 2*8, *m0 = M + 3*8;
                #pragma unroll
                for (int j = 0; j < 4; ++j) {
                    g2p(r[4*j], r[4*j+2], r[4*j+1], r[4*j+3], m1);
                    g2p(r[4*j], r[4*j+1], r[4*j+2], r[4*j+3], m0);
                }
                g2p(r[0], r[4],  r[1], r[5],  m2);
                g2p(r[2], r[6],  r[3], r[7],  m2);
                g2p(r[8], r[12], r[9], r[13], m2);
                g2p(r[10],r[14], r[11],r[15], m2);
                #pragma unroll
                for (int c = 0; c < 8; c += 2) {    // W3
                    g2p(r[c], r[c+8], r[c+1], r[c+9], m3);
                    st[rb2 + 272*c]     = r[c];
                    st[rb2 + 272*(c+1)] = r[c+1];
                    st[rb2 + 272*(c+8)] = r[c+8];
                    st[rb2 + 272*(c+9)] = r[c+9];
                    SBAR();
                }
            }
            __syncthreads();

            // F-gather: r[k] = old_amp[F((g<<4)|k)] -> canonical again
            {
                int Fg = 0;
                #pragma unroll
                for (int j = 0; j < 8; ++j)
                    Fg ^= ((g >> j) & 1) ? COLS.v[l][4 + j] : 0;
                const int c0 = COLS.v[l][0], c1 = COLS.v[l][1];
                const int c2 = COLS.v[l][2], c3 = COLS.v[l][3];
                #pragma unroll
                for (int k = 0; k < PER_T; ++k) {
                    int ck = ((k & 1) ? c0 : 0) ^ ((k & 2) ? c1 : 0) ^
                             ((k & 4) ? c2 : 0) ^ ((k & 8) ? c3 : 0);
                    r[k] = st[slotf(Fg ^ ck)];
                }
            }
            __syncthreads();   // drain F reads before next layer's W1
        }
    }

    // ---- write out (r is canonical: 16 consecutive amps per lane) ----
    if (write_mode == 0) {
        // harness views complex output as float32 real part
        float4* ob4 = (float4*)(out + (size_t)b * NSTATE) + g * 4;
        #pragma unroll
        for (int c = 0; c < 4; ++c)
            ob4[c] = make_float4(r[4*c].x, r[4*c+1].x, r[4*c+2].x, r[4*c+3].x);
    } else {
        float4* ob4 = (float4*)((float2*)out + (size_t)b * NSTATE) + g * 8;
        #pragma unroll
        for (int k = 0; k < PER_T; k += 2)
            ob4[k >> 1] = make_float4(r[k].x, r[k].y, r[k+1].x, r[k+1].y);
    }
}

extern "C" void kernel_launch(void* const* d_in, const int* in_sizes, int n_in,
                              void* d_out, int out_size, void* d_ws, size_t ws_size,
                              hipStream_t stream) {
    const float* x    = (const float*)d_in[0];
    const float* wts  = (const float*)d_in[1];
    const int*   reps = (const int*)d_in[2];
    float*       out  = (float*)d_out;
    f2*          mg   = (f2*)d_ws;            // 96 gates * 8 f2 = 3 KB scratch
    (void)in_sizes; (void)n_in; (void)ws_size;

    const int write_mode = (out_size >= 2 * 1024 * NSTATE) ? 1 : 0;

    mats_kernel<<<1, 128, 0, stream>>>(wts, mg);
    qsim_kernel<<<1024, BLOCK, 0, stream>>>(x, mg, reps, out, write_mode);
}

// Round 8
// 134.858 us; speedup vs baseline: 1.1429x; 1.0833x over previous
//
#include <hip/hip_runtime.h>

#define WIRES   12
#define NSTATE  4096          // 2^12
#define QDEPTH  8
#define BLOCK   256           // 4 waves per block = one batch element
#define PER_T   16            // 4 local index bits; state in 32 VGPRs

using f2 = __attribute__((ext_vector_type(2))) float;

// Pitch-17 padded layout: amp a -> f2-slot a + (a>>4). (Proven R1/R6.)
__device__ __forceinline__ int slotf(int a) { return a + (a >> 4); }

// Column j of the GF(2)-linear CNOT-ring permutation of layer l:
// F = g_0∘g_1∘...∘g_11 (g_11 applied first / innermost).
constexpr int colF(int l, int j) {
    int rr = (l % (WIRES - 1)) + 1;
    int v = 1 << j;
    for (int k = WIRES - 1; k >= 0; --k) {
        int bc = 11 - k;                   // control bit
        int bt = 11 - ((k + rr) % WIRES);  // target bit
        v ^= ((v >> bc) & 1) << bt;
    }
    return v;
}
struct ColsT { int v[QDEPTH][WIRES]; };
constexpr ColsT mkCols() {
    ColsT c{};
    for (int l = 0; l < QDEPTH; ++l)
        for (int j = 0; j < WIRES; ++j) c.v[l][j] = colF(l, j);
    return c;
}
static __device__ const ColsT COLS = mkCols();   // rodata, uniform s_load

// ---- workspace layout (f2 units) -- TOTAL 864 f2 = 6912 B (small!) ----
// [0,288)    RY triples: layer l, wire w -> {c,c},{-s,-s},{s,s}
// [288,544)  kfacP: layer l, k -> {c,c},{-s,+s}   (Dphi, amp bits 0..3)
// [544,800)  kfacW: layer l, k -> {c,c},{-s,+s}   (Domega, amp bits 8..11)
// [800,864)  angs:  layer l, j -> f2{angP, angW}  (lane-bit half-angles)
#define OFF_KP 288
#define OFF_KW 544
#define OFF_AN 800

// ---- setup: one block of 256 threads fills the whole table ----
// Conventions (verified against _rot_matrices):
//   Rot = RZ(omega) . RY(theta) . RZ(phi);  RZ(x): bit=0 -> e^{-ix/2},
//   bit=1 -> e^{+ix/2};  amp bit b <-> wire 11-b.
__global__ void setup_kernel(const float* __restrict__ wts, f2* __restrict__ mg)
{
    const int t = threadIdx.x;                    // 0..255
    // RY coefficient triples (real 2x2: [[c,-s],[s,c]])
    if (t < QDEPTH * WIRES) {
        float th = tanhf(wts[t * 3 + 1]);
        float c = cosf(0.5f * th), s = sinf(0.5f * th);
        mg[(t / 12) * 36 + (t % 12) * 3 + 0] = f2{ c,  c};
        mg[(t / 12) * 36 + (t % 12) * 3 + 1] = f2{-s, -s};
        mg[(t / 12) * 36 + (t % 12) * 3 + 2] = f2{ s,  s};
    }
    // lane-bit half-angles: j=0..7 <-> g bit j.
    //   Dphi  (canonical):      amp bit 4+j <-> wire 7-j,  angle phi
    //   Domega (hi-bits-local): amp bit j   <-> wire 11-j, angle omega
    if (t < 64) {
        int l = t >> 3, j = t & 7;
        float aP = 0.5f * tanhf(wts[(l * 12 + (7  - j)) * 3 + 0]);
        float aW = 0.5f * tanhf(wts[(l * 12 + (11 - j)) * 3 + 2]);
        mg[OFF_AN + l * 8 + j] = f2{aP, aW};
    }
    // per-k factors: t -> l = t>>5, k = (t>>1)&15, isW = t&1.
    //   Dphi:   k bit j = amp bit j   <-> wire 11-j, angle phi
    //   Domega: k bit j = amp bit 8+j <-> wire 3-j,  angle omega
    {
        int l = t >> 5, k = (t >> 1) & 15;
        bool isW = (t & 1) != 0;
        float ph = 0.f;
        #pragma unroll
        for (int j = 0; j < 4; ++j) {
            int wire  = isW ? (3 - j) : (11 - j);
            int comp  = isW ? 2 : 0;
            float a   = 0.5f * tanhf(wts[(l * 12 + wire) * 3 + comp]);
            ph += ((k >> j) & 1) ? a : -a;
        }
        float s, c;
        sincosf(ph, &s, &c);
        int base = isW ? OFF_KW : OFF_KP;
        mg[base + l * 32 + k * 2 + 0] = f2{ c, c};
        mg[base + l * 32 + k * 2 + 1] = f2{-s, s};
    }
}

// ---- real RY gate on reg bit P: two pairs per asm, 8 pk, chains 4 apart ----
// out0 = c*a0 - s*a1 ; out1 = s*a0 + c*a1  (acts identically on re & im).
template<int P>
__device__ __forceinline__ void gateR(f2 r[PER_T], f2 cc, f2 ms, f2 ss)
{
    #pragma unroll
    for (int pr = 0; pr < PER_T / 2; pr += 2) {
        const int k0 = ((pr >> P) << (P + 1)) | (pr & ((1 << P) - 1));
        const int k1 = k0 | (1 << P);
        const int q  = pr + 1;
        const int j0 = ((q >> P) << (P + 1)) | (q & ((1 << P) - 1));
        const int j1 = j0 | (1 << P);
        f2 a0, b0, a1, b1;
        asm("v_pk_mul_f32 %0, %4, %8\n\t"
            "v_pk_mul_f32 %1, %4, %10\n\t"
            "v_pk_mul_f32 %2, %6, %8\n\t"
            "v_pk_mul_f32 %3, %6, %10\n\t"
            "v_pk_fma_f32 %0, %5, %9, %0\n\t"
            "v_pk_fma_f32 %1, %5, %8, %1\n\t"
            "v_pk_fma_f32 %2, %7, %9, %2\n\t"
            "v_pk_fma_f32 %3, %7, %8, %3"
            : "=&v"(a0), "=&v"(b0), "=&v"(a1), "=&v"(b1)
            : "v"(r[k0]), "v"(r[k1]), "v"(r[j0]), "v"(r[j1]),
              "v"(cc), "v"(ms), "v"(ss));
        r[k0] = a0; r[k1] = b0; r[j0] = a1; r[j1] = b1;
    }
}

// Complex diag multiply on two regs: dNr = {re,re}, dNw = {-im,+im}.
// o = a*dr + a.yx*dw  -- the proven op_sel complex-multiply pattern.
__device__ __forceinline__ void dmul2(f2& a0, f2& a1, f2 d0r, f2 d0w,
                                      f2 d1r, f2 d1w)
{
    f2 o0, o1;
    asm("v_pk_mul_f32 %0, %2, %4\n\t"
        "v_pk_mul_f32 %1, %3, %6\n\t"
        "v_pk_fma_f32 %0, %2, %5, %0 op_sel:[1,0,0] op_sel_hi:[0,1,1]\n\t"
        "v_pk_fma_f32 %1, %3, %7, %1 op_sel:[1,0,0] op_sel_hi:[0,1,1]"
        : "=&v"(o0), "=&v"(o1)
        : "v"(a0), "v"(a1), "v"(d0r), "v"(d0w), "v"(d1r), "v"(d1w));
    a0 = o0; a1 = o1;
}

// Tensor-product diagonal: per-lane factor (8 signed adds + sincos) then
// 16 wave-uniform per-k factors. ~64 pk + ~20 aux.
__device__ __forceinline__ void diag(f2 r[PER_T], const f2* __restrict__ AN,
                                     const f2* __restrict__ KF, int g, bool isW)
{
    float ph = 0.f;
    #pragma unroll
    for (int j = 0; j < 8; ++j) {
        float a = isW ? AN[j].y : AN[j].x;
        ph += ((g >> j) & 1) ? a : -a;
    }
    float s, c;
    sincosf(ph, &s, &c);
    const f2 Lr = f2{c, c}, Lw = f2{-s, s};
    #pragma unroll
    for (int k = 0; k < PER_T; k += 2)
        dmul2(r[k], r[k + 1], Lr, Lw, Lr, Lw);
    #pragma unroll
    for (int k = 0; k < PER_T; k += 2)
        dmul2(r[k], r[k + 1], KF[2*k], KF[2*k + 1], KF[2*k + 2], KF[2*k + 3]);
}

// 4 waves = one batch element. g = threadIdx.x (8 bits).
// Canonical: r[k] = amp[(g<<4)|k]  (amp bit b <-> wire 11-b).
// Per layer (layer U = Domega . Y . Dphi; P*(...) applied last):
//   Dphi (canonical tensor diag)
//   P1: RY wires 8..11 (amp bits 3..0) -> W1 -> R1
//   P2: RY wires 4..7  (amp bits 7..4) -> W2 -> R2
//   P3: RY wires 0..3  (amp bits 11..8)
//   Domega (tensor diag in hi-bits-local layout)
//   W3 -> F-gather (CNOT ring folded) -> canonical
// LDS skeleton, addressing, barriers identical to the proven R1/R6 kernel.
__global__ __launch_bounds__(BLOCK, 4) void qsim_kernel(
    const float* __restrict__ x,
    const f2*    __restrict__ mg,
    const int*   __restrict__ reps_ptr,
    float*       __restrict__ out,
    int write_mode)
{
    __shared__ f2 st[4352];                          // 34816 B -> 4 blocks/CU

    const int g   = threadIdx.x;
    const int b   = blockIdx.x;
    const int ghi = g >> 4, glo = g & 15;
    const int w1b = 17 * g;                // slot((g<<4)|k)          = 17g + k
    const int rb1 = 272 * ghi + glo;       // slot((ghi<<8)|(k<<4)|glo) - 17k
    const int rb2 = 17 * ghi + glo;        // slot((k<<8)|(ghi<<4)|glo) - 272k

    // ---- load: lane g holds amps (g<<4)|k, k=0..15 (64B contiguous) ----
    const float4* xb4 = (const float4*)(x + (size_t)b * NSTATE) + g * 4;
    f2 r[PER_T];
    #pragma unroll
    for (int c = 0; c < 4; ++c) {
        float4 v = xb4[c];
        r[4*c+0] = f2{v.x, 0.f};
        r[4*c+1] = f2{v.y, 0.f};
        r[4*c+2] = f2{v.z, 0.f};
        r[4*c+3] = f2{v.w, 0.f};
    }

    const int reps = reps_ptr[0];
    for (int rep = 0; rep < reps; ++rep) {
        #pragma unroll 1
        for (int l = 0; l < QDEPTH; ++l) {
            const f2* CS = mg + l * 36;              // RY triples (wire*3)
            const f2* KP = mg + OFF_KP + l * 32;
            const f2* KW = mg + OFF_KW + l * 32;
            const f2* AN = mg + OFF_AN + l * 8;

            // Dphi (canonical layout)
            diag(r, AN, KP, g, false);

            // P1: wires 8..11 on local bits 3..0 (amp bit = 11-wire)
            gateR<3>(r, CS[8*3],  CS[8*3+1],  CS[8*3+2]);
            gateR<2>(r, CS[9*3],  CS[9*3+1],  CS[9*3+2]);
            gateR<1>(r, CS[10*3], CS[10*3+1], CS[10*3+2]);
            gateR<0>(r, CS[11*3], CS[11*3+1], CS[11*3+2]);

            #pragma unroll
            for (int k = 0; k < PER_T; ++k) st[w1b + k] = r[k];
            __syncthreads();
            #pragma unroll
            for (int k = 0; k < PER_T; ++k) r[k] = st[rb1 + 17 * k];
            // no barrier: W2 rewrites exactly the slots this lane just read

            // P2: wires 4..7 (amp bits 7..4 local; local bit P <-> wire 7-P)
            gateR<3>(r, CS[4*3], CS[4*3+1], CS[4*3+2]);
            gateR<2>(r, CS[5*3], CS[5*3+1], CS[5*3+2]);
            gateR<1>(r, CS[6*3], CS[6*3+1], CS[6*3+2]);
            gateR<0>(r, CS[7*3], CS[7*3+1], CS[7*3+2]);

            #pragma unroll
            for (int k = 0; k < PER_T; ++k) st[rb1 + 17 * k] = r[k];
            __syncthreads();
            #pragma unroll
            for (int k = 0; k < PER_T; ++k) r[k] = st[rb2 + 272 * k];

            // P3: wires 0..3 (amp bits 11..8 local; local bit P <-> wire 3-P)
            gateR<3>(r, CS[0*3], CS[0*3+1], CS[0*3+2]);
            gateR<2>(r, CS[1*3], CS[1*3+1], CS[1*3+2]);
            gateR<1>(r, CS[2*3], CS[2*3+1], CS[2*3+2]);
            gateR<0>(r, CS[3*3], CS[3*3+1], CS[3*3+2]);

            // Domega (hi-bits-local layout: amp bits 0..7 = g bits 0..7,
            // amp bits 8..11 = k bits 0..3)
            diag(r, AN, KW, g, true);

            #pragma unroll
            for (int k = 0; k < PER_T; ++k) st[rb2 + 272 * k] = r[k];
            __syncthreads();

            // F-gather: r[k] = old_amp[F((g<<4)|k)] -> canonical again
            {
                int Fg = 0;
                #pragma unroll
                for (int j = 0; j < 8; ++j)
                    Fg ^= ((g >> j) & 1) ? COLS.v[l][4 + j] : 0;
                const int c0 = COLS.v[l][0], c1 = COLS.v[l][1];
                const int c2 = COLS.v[l][2], c3 = COLS.v[l][3];
                #pragma unroll
                for (int k = 0; k < PER_T; ++k) {
                    int ck = ((k & 1) ? c0 : 0) ^ ((k & 2) ? c1 : 0) ^
                             ((k & 4) ? c2 : 0) ^ ((k & 8) ? c3 : 0);
                    r[k] = st[slotf(Fg ^ ck)];
                }
            }
            __syncthreads();   // drain F reads before next layer's W1
        }
    }

    // ---- write out (r is canonical: 16 consecutive amps per lane) ----
    if (write_mode == 0) {
        // harness views complex output as float32 real part
        float4* ob4 = (float4*)(out + (size_t)b * NSTATE) + g * 4;
        #pragma unroll
        for (int c = 0; c < 4; ++c)
            ob4[c] = make_float4(r[4*c].x, r[4*c+1].x, r[4*c+2].x, r[4*c+3].x);
    } else {
        float4* ob4 = (float4*)((float2*)out + (size_t)b * NSTATE) + g * 8;
        #pragma unroll
        for (int k = 0; k < PER_T; k += 2)
            ob4[k >> 1] = make_float4(r[k].x, r[k].y, r[k+1].x, r[k+1].y);
    }
}

extern "C" void kernel_launch(void* const* d_in, const int* in_sizes, int n_in,
                              void* d_out, int out_size, void* d_ws, size_t ws_size,
                              hipStream_t stream) {
    const float* x    = (const float*)d_in[0];
    const float* wts  = (const float*)d_in[1];
    const int*   reps = (const int*)d_in[2];
    float*       out  = (float*)d_out;
    f2*          mg   = (f2*)d_ws;            // 864 f2 = 6912 B scratch
    (void)in_sizes; (void)n_in; (void)ws_size;

    const int write_mode = (out_size >= 2 * 1024 * NSTATE) ? 1 : 0;

    setup_kernel<<<1, 256, 0, stream>>>(wts, mg);
    qsim_kernel<<<1024, BLOCK, 0, stream>>>(x, mg, reps, out, write_mode);
}